// Round 2
// baseline (290.320 us; speedup 1.0000x reference)
//
#include <hip/hip_runtime.h>

typedef __attribute__((ext_vector_type(4))) float f32x4;
typedef __attribute__((ext_vector_type(8))) __bf16 bf16x8;

#define LOG_2PI 1.8378770664093453f

__device__ __forceinline__ float softplus_f(float x) {
  return fmaxf(x, 0.f) + log1pf(expf(-fabsf(x)));
}

// ---------------- marks_proj = event_marks @ Wp + bp  (1024x128, K=128) ----
__global__ void marks_kernel(const float* __restrict__ em,
                             const float* __restrict__ Wp,
                             const float* __restrict__ bp,
                             float* __restrict__ mp) {
  const int e = blockIdx.x;
  const int d = threadIdx.x;
  float s = bp[d];
  const float* emr = em + e * 128;
#pragma unroll 4
  for (int k = 0; k < 128; ++k) s += emr[k] * Wp[k * 128 + d];
  mp[e * 128 + d] = s;
}

// ---------------- intensity kernels ----------------------------------------
// rows = ntiles*32 of z (row-major, 128 wide). Per block: 8 waves, wave w owns
// hidden cols [64w,64w+64). h = relu(z@W1+b1); s = h@W2+b2+base; lam=softplus(s).
// MODE 0 (traj): acc += lam*dt/64, kl += z^2.  MODE 1 (events): acc += log(lam+1e-8)/64.
template <int MODE>
__global__ __launch_bounds__(512) void intensity_kernel(
    const float* __restrict__ z, int ntiles,
    const float* __restrict__ W1, const float* __restrict__ b1,
    const float* __restrict__ W2, const float* __restrict__ b2,
    const float* __restrict__ base_i, const float* __restrict__ times,
    float* __restrict__ out_acc, float* __restrict__ kl_acc) {
  __shared__ __align__(16) __bf16 zbuf[2][32 * 128];
  __shared__ float s_part[32][8];
  __shared__ float red[8];

  const int tid = threadIdx.x;
  const int wid = tid >> 6, lid = tid & 63;
  const int g = lid >> 4, q = lid & 15;
  const int cb = wid * 64;

  // W1 fragments: [cf][kf], lane (g,q), elem j -> W1[kf*32+g*8+j][cb+cf*16+q]
  bf16x8 bw[4][4];
  float b1v[4], w2v[4];
#pragma unroll
  for (int cf = 0; cf < 4; ++cf) {
    const int col = cb + cf * 16 + q;
    b1v[cf] = b1[col];
    w2v[cf] = W2[col];
#pragma unroll
    for (int kf = 0; kf < 4; ++kf) {
      bf16x8 f;
#pragma unroll
      for (int j = 0; j < 8; ++j) f[j] = (__bf16)W1[(kf * 32 + g * 8 + j) * 512 + col];
      bw[cf][kf] = f;
    }
  }
  const float sbias = b2[0] + base_i[0];

  // staging: each thread 8 f32 -> 8 bf16 (16B) ; row=tid>>4, k8=(tid&15)*8
  const int srow = tid >> 4;
  const int sk8 = (tid & 15) * 8;
  const int stg_byte = ((srow * 256 + sk8 * 2) ^ ((srow & 7) << 4));

  float local = 0.f, kls = 0.f;

  int tile = blockIdx.x;
  const int stride = gridDim.x;

  if (tile < ntiles) {  // prologue: stage first tile into buf 0
    const float* p = z + (size_t)tile * 4096 + tid * 8;
    f32x4 r0 = *(const f32x4*)p;
    f32x4 r1 = *(const f32x4*)(p + 4);
    if (MODE == 0) {
      kls += r0[0] * r0[0] + r0[1] * r0[1] + r0[2] * r0[2] + r0[3] * r0[3];
      kls += r1[0] * r1[0] + r1[1] * r1[1] + r1[2] * r1[2] + r1[3] * r1[3];
    }
    bf16x8 v;
#pragma unroll
    for (int j = 0; j < 4; ++j) { v[j] = (__bf16)r0[j]; v[4 + j] = (__bf16)r1[j]; }
    *(bf16x8*)((char*)zbuf[0] + stg_byte) = v;
  }
  __syncthreads();

  int cur = 0;
  while (tile < ntiles) {
    const int nt = tile + stride;
    const bool has = nt < ntiles;
    f32x4 r0, r1;
    if (has) {
      const float* p = z + (size_t)nt * 4096 + tid * 8;
      r0 = *(const f32x4*)p;
      r1 = *(const f32x4*)(p + 4);
    }

    // GEMM: 32x512 += 32x128 * 128x512 (per wave: 32x64)
    f32x4 acc[2][4] = {};
    char* zc = (char*)zbuf[cur];
#pragma unroll
    for (int kf = 0; kf < 4; ++kf) {
#pragma unroll
      for (int rf = 0; rf < 2; ++rf) {
        const int row = rf * 16 + q;
        bf16x8 a = *(const bf16x8*)(zc + ((row * 256 + kf * 64 + g * 16) ^ ((row & 7) << 4)));
#pragma unroll
        for (int cf = 0; cf < 4; ++cf)
          acc[rf][cf] = __builtin_amdgcn_mfma_f32_16x16x32_bf16(a, bw[cf][kf], acc[rf][cf], 0, 0, 0);
      }
    }

    if (has) {  // finish prefetch: convert + write other buffer
      if (MODE == 0) {
        kls += r0[0] * r0[0] + r0[1] * r0[1] + r0[2] * r0[2] + r0[3] * r0[3];
        kls += r1[0] * r1[0] + r1[1] * r1[1] + r1[2] * r1[2] + r1[3] * r1[3];
      }
      bf16x8 v;
#pragma unroll
      for (int j = 0; j < 4; ++j) { v[j] = (__bf16)r0[j]; v[4 + j] = (__bf16)r1[j]; }
      *(bf16x8*)((char*)zbuf[cur ^ 1] + stg_byte) = v;
    }

    // epilogue: per-row s partials; D layout row=(g*4+i), col=q
#pragma unroll
    for (int rf = 0; rf < 2; ++rf) {
      float p0 = 0.f, p1 = 0.f, p2 = 0.f, p3 = 0.f;
#pragma unroll
      for (int cf = 0; cf < 4; ++cf) {
        p0 += fmaxf(acc[rf][cf][0] + b1v[cf], 0.f) * w2v[cf];
        p1 += fmaxf(acc[rf][cf][1] + b1v[cf], 0.f) * w2v[cf];
        p2 += fmaxf(acc[rf][cf][2] + b1v[cf], 0.f) * w2v[cf];
        p3 += fmaxf(acc[rf][cf][3] + b1v[cf], 0.f) * w2v[cf];
      }
#pragma unroll
      for (int m = 1; m < 16; m <<= 1) {
        p0 += __shfl_xor(p0, m);
        p1 += __shfl_xor(p1, m);
        p2 += __shfl_xor(p2, m);
        p3 += __shfl_xor(p3, m);
      }
      const float pv = (q == 0) ? p0 : (q == 1) ? p1 : (q == 2) ? p2 : p3;
      if (q < 4) s_part[rf * 16 + g * 4 + q][wid] = pv;
    }
    __syncthreads();

    if (tid < 32) {
      float s = sbias;
#pragma unroll
      for (int w = 0; w < 8; ++w) s += s_part[tid][w];
      const float lam = softplus_f(s);
      if (MODE == 0) {
        const int r = tile * 32 + tid;
        const int t = r >> 6;
        local += lam * (times[t + 1] - times[t]) * (1.f / 64.f);
      } else {
        local += logf(lam + 1e-8f) * (1.f / 64.f);
      }
    }
    __syncthreads();
    cur ^= 1;
    tile = nt;
  }

  // block reduction(s) + atomic
#pragma unroll
  for (int m = 32; m >= 1; m >>= 1) local += __shfl_xor(local, m);
  if (lid == 0) red[wid] = local;
  __syncthreads();
  if (tid == 0) {
    float s = 0.f;
    for (int w = 0; w < 8; ++w) s += red[w];
    atomicAdd(out_acc, s);
  }
  if (MODE == 0) {
    __syncthreads();
#pragma unroll
    for (int m = 32; m >= 1; m >>= 1) kls += __shfl_xor(kls, m);
    if (lid == 0) red[wid] = kls;
    __syncthreads();
    if (tid == 0) {
      float s = 0.f;
      for (int w = 0; w < 8; ++w) s += red[w];
      atomicAdd(kl_acc, s);
    }
  }
}

// ---------------- decoder: h=relu(z@Wd1+bd1); mu=h@Wd2+bd2; logp ------------
__global__ __launch_bounds__(512) void decoder_kernel(
    const float* __restrict__ z, int ntiles,
    const float* __restrict__ Wd1, const float* __restrict__ bd1,
    const float* __restrict__ Wd2, const float* __restrict__ bd2,
    const float* __restrict__ mp, float* __restrict__ recon_acc) {
  __shared__ __align__(16) __bf16 zbuf[2][32 * 128];
  __shared__ __align__(16) __bf16 hbuf[32 * 512];
  __shared__ float s_part[32][8];
  __shared__ float red[8];

  const int tid = threadIdx.x;
  const int wid = tid >> 6, lid = tid & 63;
  const int g = lid >> 4, q = lid & 15;
  const int cb = wid * 64;

  bf16x8 bw1[4][4];
  float bd1v[4];
#pragma unroll
  for (int cf = 0; cf < 4; ++cf) {
    const int col = cb + cf * 16 + q;
    bd1v[cf] = bd1[col];
#pragma unroll
    for (int kf = 0; kf < 4; ++kf) {
      bf16x8 f;
#pragma unroll
      for (int j = 0; j < 8; ++j) f[j] = (__bf16)Wd1[(kf * 32 + g * 8 + j) * 512 + col];
      bw1[cf][kf] = f;
    }
  }
  const int col2 = wid * 16 + q;  // mu column owned by this lane
  const float bd2v = bd2[col2];
  bf16x8 bw2[16];
#pragma unroll
  for (int kf = 0; kf < 16; ++kf) {
    bf16x8 f;
#pragma unroll
    for (int j = 0; j < 8; ++j) f[j] = (__bf16)Wd2[(kf * 32 + g * 8 + j) * 128 + col2];
    bw2[kf] = f;
  }

  const int srow = tid >> 4;
  const int sk8 = (tid & 15) * 8;
  const int stg_byte = ((srow * 256 + sk8 * 2) ^ ((srow & 7) << 4));
  char* hb = (char*)hbuf;

  float local = 0.f;

  int tile = blockIdx.x;
  const int stride = gridDim.x;

  if (tile < ntiles) {
    const float* p = z + (size_t)tile * 4096 + tid * 8;
    f32x4 r0 = *(const f32x4*)p;
    f32x4 r1 = *(const f32x4*)(p + 4);
    bf16x8 v;
#pragma unroll
    for (int j = 0; j < 4; ++j) { v[j] = (__bf16)r0[j]; v[4 + j] = (__bf16)r1[j]; }
    *(bf16x8*)((char*)zbuf[0] + stg_byte) = v;
  }
  __syncthreads();

  int cur = 0;
  while (tile < ntiles) {
    const int nt = tile + stride;
    const bool has = nt < ntiles;
    f32x4 r0, r1;
    if (has) {
      const float* p = z + (size_t)nt * 4096 + tid * 8;
      r0 = *(const f32x4*)p;
      r1 = *(const f32x4*)(p + 4);
    }

    // GEMM1: h(32x512)
    f32x4 acc1[2][4] = {};
    char* zc = (char*)zbuf[cur];
#pragma unroll
    for (int kf = 0; kf < 4; ++kf) {
#pragma unroll
      for (int rf = 0; rf < 2; ++rf) {
        const int row = rf * 16 + q;
        bf16x8 a = *(const bf16x8*)(zc + ((row * 256 + kf * 64 + g * 16) ^ ((row & 7) << 4)));
#pragma unroll
        for (int cf = 0; cf < 4; ++cf)
          acc1[rf][cf] = __builtin_amdgcn_mfma_f32_16x16x32_bf16(a, bw1[cf][kf], acc1[rf][cf], 0, 0, 0);
      }
    }

    // write h tile to LDS (bf16, swizzled on row bits 1..3)
#pragma unroll
    for (int rf = 0; rf < 2; ++rf) {
#pragma unroll
      for (int cf = 0; cf < 4; ++cf) {
#pragma unroll
        for (int i = 0; i < 4; ++i) {
          const int row = rf * 16 + g * 4 + i;
          const int col = cb + cf * 16 + q;
          const float h = fmaxf(acc1[rf][cf][i] + bd1v[cf], 0.f);
          const int byt = ((row * 1024 + col * 2) ^ (((row >> 1) & 7) << 4));
          *(__bf16*)(hb + byt) = (__bf16)h;
        }
      }
    }

    if (has) {
      bf16x8 v;
#pragma unroll
      for (int j = 0; j < 4; ++j) { v[j] = (__bf16)r0[j]; v[4 + j] = (__bf16)r1[j]; }
      *(bf16x8*)((char*)zbuf[cur ^ 1] + stg_byte) = v;
    }
    __syncthreads();  // h ready

    // GEMM2: mu(32x128) = h(32x512) @ Wd2
    f32x4 acc2[2] = {};
#pragma unroll
    for (int kf = 0; kf < 16; ++kf) {
#pragma unroll
      for (int rf = 0; rf < 2; ++rf) {
        const int row = rf * 16 + q;
        bf16x8 a = *(const bf16x8*)(hb + ((row * 1024 + kf * 64 + g * 16) ^ (((row >> 1) & 7) << 4)));
        acc2[rf] = __builtin_amdgcn_mfma_f32_16x16x32_bf16(a, bw2[kf], acc2[rf], 0, 0, 0);
      }
    }

    const int e = (tile * 32) >> 6;  // constant over the tile
    const float xv = mp[e * 128 + col2];
#pragma unroll
    for (int rf = 0; rf < 2; ++rf) {
      float d0 = xv - (acc2[rf][0] + bd2v);
      float d1 = xv - (acc2[rf][1] + bd2v);
      float d2 = xv - (acc2[rf][2] + bd2v);
      float d3 = xv - (acc2[rf][3] + bd2v);
      float p0 = d0 * d0, p1 = d1 * d1, p2 = d2 * d2, p3 = d3 * d3;
#pragma unroll
      for (int m = 1; m < 16; m <<= 1) {
        p0 += __shfl_xor(p0, m);
        p1 += __shfl_xor(p1, m);
        p2 += __shfl_xor(p2, m);
        p3 += __shfl_xor(p3, m);
      }
      const float pv = (q == 0) ? p0 : (q == 1) ? p1 : (q == 2) ? p2 : p3;
      if (q < 4) s_part[rf * 16 + g * 4 + q][wid] = pv;
    }
    __syncthreads();

    if (tid < 32) {
      float t = 0.f;
#pragma unroll
      for (int w = 0; w < 8; ++w) t += s_part[tid][w];
      local += (-0.5f * t - 0.5f * 128.f * LOG_2PI) * (1.f / 64.f);
    }
    __syncthreads();
    cur ^= 1;
    tile = nt;
  }

#pragma unroll
  for (int m = 32; m >= 1; m >>= 1) local += __shfl_xor(local, m);
  if (lid == 0) red[wid] = local;
  __syncthreads();
  if (tid == 0) {
    float s = 0.f;
    for (int w = 0; w < 8; ++w) s += red[w];
    atomicAdd(recon_acc, s);
  }
}

// ---------------- finalize --------------------------------------------------
__global__ void finalize_kernel(const float* __restrict__ accs, float* __restrict__ out) {
  // accs: [0]=integral, [1]=log_intensity_sum, [2]=recon, [3]=sum(z_traj^2)
  const float kl = 0.01f * (accs[3] / 67108864.f);  // 8192*64*128
  const float elbo = accs[1] - accs[0] + accs[2] - kl;
  out[0] = -elbo;
}

extern "C" void kernel_launch(void* const* d_in, const int* in_sizes, int n_in,
                              void* d_out, int out_size, void* d_ws, size_t ws_size,
                              hipStream_t stream) {
  const float* event_marks = (const float*)d_in[0];
  const float* z_events = (const float*)d_in[1];
  const float* z_traj = (const float*)d_in[2];
  const float* times = (const float*)d_in[3];
  const float* Wp = (const float*)d_in[4];
  const float* bp = (const float*)d_in[5];
  const float* W1 = (const float*)d_in[6];
  const float* b1 = (const float*)d_in[7];
  const float* W2 = (const float*)d_in[8];
  const float* b2 = (const float*)d_in[9];
  const float* base_i = (const float*)d_in[10];
  const float* Wd1 = (const float*)d_in[11];
  const float* bd1 = (const float*)d_in[12];
  const float* Wd2 = (const float*)d_in[13];
  const float* bd2 = (const float*)d_in[14];

  float* mp = (float*)d_ws;                                   // 1024*128 f32
  float* accs = (float*)((char*)d_ws + 1024 * 128 * 4);       // 4 f32 accumulators

  (void)hipMemsetAsync(accs, 0, 4 * sizeof(float), stream);
  marks_kernel<<<1024, 128, 0, stream>>>(event_marks, Wp, bp, mp);
  // z_traj: 524288 rows -> 16384 tiles of 32
  intensity_kernel<0><<<1024, 512, 0, stream>>>(z_traj, 16384, W1, b1, W2, b2,
                                                base_i, times, &accs[0], &accs[3]);
  // z_events: 65536 rows -> 2048 tiles of 32
  intensity_kernel<1><<<512, 512, 0, stream>>>(z_events, 2048, W1, b1, W2, b2,
                                               base_i, times, &accs[1], nullptr);
  decoder_kernel<<<512, 512, 0, stream>>>(z_events, 2048, Wd1, bd1, Wd2, bd2,
                                          mp, &accs[2]);
  finalize_kernel<<<1, 1, 0, stream>>>(accs, (float*)d_out);
}